// Round 6
// baseline (108.462 us; speedup 1.0000x reference)
//
#include <hip/hip_runtime.h>
#include <math.h>

#define DD 128
#define HH 128
#define WW 128
#define NN (DD*HH*WW)
#define DJ 127

// workspace slots (doubles)
#define NB_LNCC 4096
#define NB_FUSED 2048
#define LOFF 0
#define GOFF (NB_LNCC)
#define JOFF (NB_LNCC + NB_FUSED)
#define IOFF (NB_LNCC + 2*NB_FUSED)

// ---------- small helpers ----------
__device__ __forceinline__ double wave_reduce(double v) {
    #pragma unroll
    for (int o = 32; o > 0; o >>= 1) v += __shfl_down(v, o);
    return v;
}

template <int NWAVES>
__device__ __forceinline__ double block_reduce(double v, double* red, int tid) {
    v = wave_reduce(v);
    int wid = tid >> 6, lane = tid & 63;
    __syncthreads();
    if (lane == 0) red[wid] = v;
    __syncthreads();
    double x = 0.0;
    if (tid == 0) {
        #pragma unroll
        for (int w = 0; w < NWAVES; w++) x += red[w];
    }
    return x;
}

__device__ __forceinline__ float4 add4(float4 a, float4 b) {
    return make_float4(a.x + b.x, a.y + b.y, a.z + b.z, a.w + b.w);
}

__device__ __forceinline__ float jac_term(const float* dz_, const float* dy_, const float* dx_) {
    float a00 = 1.f + dz_[0], a01 = dy_[0], a02 = dx_[0];
    float a10 = dz_[1], a11 = 1.f + dy_[1], a12 = dx_[1];
    float a20 = dz_[2], a21 = dy_[2], a22 = 1.f + dx_[2];
    float det = a00 * (a11 * a22 - a12 * a21)
              - a01 * (a10 * a22 - a12 * a20)
              + a02 * (a10 * a21 - a11 * a20);
    if (isnan(det)) det = 0.f;
    else if (isinf(det)) det = det > 0.f ? 1000.f : -1000.f;
    float neg = -det;
    return neg > 0.f ? neg : 0.f;
}

// ============ mega-kernel: co-scheduled lncc + fused ============
// 6144 blocks x 512 threads. bid%3==2 -> fused role (2048 blocks),
// else lncc role (4096 blocks). Roles interleave in dispatch order so both
// are co-resident per CU; fused gather latency hides under lncc LDS/VALU work.
// Both roles are XCD-z-slab-chunked: blocks on XCD j (bid&7==j) process
// z in [16j, 16j+16), keeping fwd/bwd/src/tgt slabs hot in that XCD's L2.
__global__ __launch_bounds__(512) void mega_kernel(const float* __restrict__ src,
                                                   const float* __restrict__ tgt,
                                                   const float* __restrict__ fwd,
                                                   const float* __restrict__ bwd,
                                                   double* __restrict__ ws) {
    __shared__ __align__(16) float F1[5][12 * 12 * 8];   // x-summed moments
    __shared__ __align__(16) float F2[5][12 * 8 * 8];    // xy-summed moments
    __shared__ double red[8];
    const int tid = threadIdx.x;
    const int bid = blockIdx.x;
    const int xcd = bid & 7;

    if (bid % 3 == 2) {
        // ================= fused role: grad + jac + inverse-consistency =================
        const int fid = bid / 3;
        // xcd-chunked: (3*fid+2)&7 == bid&7; each XCD gets contiguous swz range.
        const int swz = xcd * 256 + (fid >> 3);            // bijective over 0..2047
        const int t2 = (swz * 512 + tid) * 2;              // 2 voxels per thread
        const int x = t2 & 127; int rr = t2 >> 7; const int y = rr & 127; const int z = rr >> 7;
        const bool hy = (y < HH - 1), hz = (z < DD - 1);

        double accG = 0.0, accJ = 0.0, accI = 0.0;

        float va[3][2];
        float d0x[3], d0y[3], d0z[3], d1x[3], d1y[3], d1z[3];
        #pragma unroll
        for (int c = 0; c < 3; c++) {
            const float* p = fwd + c * NN + t2;
            float2 q = *(const float2*)p;
            float x2v = (x < WW - 2) ? p[2] : 0.f;
            float2 qy = hy ? *(const float2*)(p + WW) : make_float2(0.f, 0.f);
            float2 qz = hz ? *(const float2*)(p + WW * HH) : make_float2(0.f, 0.f);
            va[c][0] = q.x; va[c][1] = q.y;
            d0x[c] = q.y - q.x;                         // voxel0: x <= 126, valid
            d1x[c] = (x < WW - 2) ? (x2v - q.y) : 0.f;
            d0y[c] = hy ? (qy.x - q.x) : 0.f;
            d1y[c] = hy ? (qy.y - q.y) : 0.f;
            d0z[c] = hz ? (qz.x - q.x) : 0.f;
            d1z[c] = hz ? (qz.y - q.y) : 0.f;
        }

        // grad3d L2 (both voxels)
        {
            float g = 0.f;
            #pragma unroll
            for (int c = 0; c < 3; c++) {
                g = fmaf(d0x[c], d0x[c], g); g = fmaf(d0y[c], d0y[c], g); g = fmaf(d0z[c], d0z[c], g);
                g = fmaf(d1x[c], d1x[c], g); g = fmaf(d1y[c], d1y[c], g); g = fmaf(d1z[c], d1z[c], g);
            }
            accG += (double)g;
        }

        // negative Jacobian (interior 127^3)
        if (hy && hz) {
            accJ += (double)jac_term(d0z, d0y, d0x);
            if (x < WW - 2) accJ += (double)jac_term(d1z, d1y, d1x);
        }

        // inverse consistency: planar trilinear gather
        #pragma unroll
        for (int j = 0; j < 2; j++) {
            const int xj = x + j;
            float v0 = va[0][j], v1 = va[1][j], v2 = va[2][j];
            float cz = fminf(fmaxf((float)z + v0, 0.f), (float)(DD - 1));
            float cy = fminf(fmaxf((float)y + v1, 0.f), (float)(HH - 1));
            float cx = fminf(fmaxf((float)xj + v2, 0.f), (float)(WW - 1));
            float z0f = floorf(cz), y0f = floorf(cy), x0f = floorf(cx);
            float fz = cz - z0f, fy = cy - y0f, fx = cx - x0f;
            int z0 = (int)z0f, y0 = (int)y0f, x0 = (int)x0f;
            int z1 = min(z0 + 1, DD - 1), y1 = min(y0 + 1, HH - 1), x1 = min(x0 + 1, WW - 1);
            int i000 = (z0 * HH + y0) * WW + x0, i001 = (z0 * HH + y0) * WW + x1;
            int i010 = (z0 * HH + y1) * WW + x0, i011 = (z0 * HH + y1) * WW + x1;
            int i100 = (z1 * HH + y0) * WW + x0, i101 = (z1 * HH + y0) * WW + x1;
            int i110 = (z1 * HH + y1) * WW + x0, i111 = (z1 * HH + y1) * WW + x1;
            float w000 = (1.f - fz) * (1.f - fy) * (1.f - fx);
            float w001 = (1.f - fz) * (1.f - fy) * fx;
            float w010 = (1.f - fz) * fy * (1.f - fx);
            float w011 = (1.f - fz) * fy * fx;
            float w100 = fz * (1.f - fy) * (1.f - fx);
            float w101 = fz * (1.f - fy) * fx;
            float w110 = fz * fy * (1.f - fx);
            float w111 = fz * fy * fx;
            float vv[3] = {v0, v1, v2};
            #pragma unroll
            for (int c = 0; c < 3; c++) {
                const float* b = bwd + c * NN;
                float warped = w000 * b[i000] + w001 * b[i001]
                             + w010 * b[i010] + w011 * b[i011]
                             + w100 * b[i100] + w101 * b[i101]
                             + w110 * b[i110] + w111 * b[i111];
                float comp = vv[c] + warped;
                accI += (double)(comp * comp);
            }
        }

        double tG = block_reduce<8>(accG, red, tid);
        double tJ = block_reduce<8>(accJ, red, tid);
        double tI = block_reduce<8>(accI, red, tid);
        if (tid == 0) {
            ws[GOFF + swz] = tG;
            ws[JOFF + swz] = tJ;
            ws[IOFF + swz] = tI;
        }
        return;
    }

    // ================= lncc role: separable 5^3 box filter =================
    // Map this block to a unique (xcd, idx) with idx in 0..511:
    // rems on this xcd within a period of 24: {xcd, xcd+8, xcd+16}; exactly one
    // has %3==2 (fused). The other two (ascending lo<hi) are lncc.
    const int g24 = bid / 24;
    const int rem = bid % 24;
    int lo, hi;
    {
        int t0 = xcd, t1 = xcd + 8, t2r = xcd + 16;
        if (t0 % 3 == 2)      { lo = t1; hi = t2r; }
        else if (t1 % 3 == 2) { lo = t0; hi = t2r; }
        else                  { lo = t0; hi = t1; }
    }
    const int idx = g24 * 2 + (rem == hi ? 1 : 0);          // 0..511 within xcd
    const int slot = xcd * 512 + idx;                       // unique 0..4095
    // xcd-chunked tiles: z-slab [16*xcd, 16*xcd+16)
    const int bz = xcd * 16 + (idx >> 8) * 8;
    const int by = ((idx >> 4) & 15) * 8;
    const int bx = (idx & 15) * 8;

    // ---- x-pass: one half-row (4 outputs) per thread, 288 tasks ----
    if (tid < 288) {
        const int h = tid & 1;
        const int row = tid >> 1;
        const int ly = row % 12, lz = row / 12;
        const int gy = by + ly - 2, gz = bz + lz - 2;
        const bool rowok = (gy >= 0 && gy < HH && gz >= 0 && gz < DD);
        const int rowbase = (gz * HH + gy) * WW;
        const int w0 = bx + h * 4 - 4;            // aligned float4 window start

        float4 lsv[3], ltv[3];
        #pragma unroll
        for (int p = 0; p < 3; p++) {
            int gx = w0 + 4 * p;
            if (rowok && gx >= 0 && gx <= WW - 4) {
                lsv[p] = *(const float4*)(src + rowbase + gx);
                ltv[p] = *(const float4*)(tgt + rowbase + gx);
            } else {
                lsv[p] = make_float4(0.f, 0.f, 0.f, 0.f);
                ltv[p] = make_float4(0.f, 0.f, 0.f, 0.f);
            }
        }
        const float* ls = (const float*)lsv;   // 12 values, static-indexed below
        const float* lt = (const float*)ltv;

        float o[5][4];
        #pragma unroll
        for (int k = 0; k < 4; k++) {
            float s1 = 0.f, t1s = 0.f, s2 = 0.f, t2s = 0.f, st = 0.f;
            #pragma unroll
            for (int d = 0; d < 5; d++) {
                float a = ls[k + d + 2], b = lt[k + d + 2];
                s1 += a; t1s += b;
                s2 = fmaf(a, a, s2); t2s = fmaf(b, b, t2s); st = fmaf(a, b, st);
            }
            o[0][k] = s1; o[1][k] = t1s; o[2][k] = s2; o[3][k] = t2s; o[4][k] = st;
        }
        const int obase = (lz * 12 + ly) * 8 + h * 4;
        #pragma unroll
        for (int f = 0; f < 5; f++)
            *(float4*)&F1[f][obase] = make_float4(o[f][0], o[f][1], o[f][2], o[f][3]);
    }
    __syncthreads();

    // ---- y-pass: 4 outputs per thread, 192 tasks ----
    if (tid < 192) {
        const int h = tid & 1;
        const int r = tid >> 1;
        const int oy = r & 7, lz = r >> 3;
        float4 a0 = make_float4(0.f, 0.f, 0.f, 0.f), a1 = a0, a2 = a0, a3 = a0, a4 = a0;
        #pragma unroll
        for (int dy = 0; dy < 5; dy++) {
            const int j = (lz * 12 + oy + dy) * 8 + h * 4;
            a0 = add4(a0, *(const float4*)&F1[0][j]);
            a1 = add4(a1, *(const float4*)&F1[1][j]);
            a2 = add4(a2, *(const float4*)&F1[2][j]);
            a3 = add4(a3, *(const float4*)&F1[3][j]);
            a4 = add4(a4, *(const float4*)&F1[4][j]);
        }
        const int jo = (lz * 8 + oy) * 8 + h * 4;
        *(float4*)&F2[0][jo] = a0;
        *(float4*)&F2[1][jo] = a1;
        *(float4*)&F2[2][jo] = a2;
        *(float4*)&F2[3][jo] = a3;
        *(float4*)&F2[4][jo] = a4;
    }
    __syncthreads();

    // ---- z-pass + lncc: 4 voxels per thread, 128 tasks ----
    double lsum = 0.0;
    if (tid < 128) {
        const int h = tid & 1;
        const int r = tid >> 1;
        const int oy = r & 7, oz = r >> 3;
        float A[5][4];
        #pragma unroll
        for (int f = 0; f < 5; f++) { A[f][0] = A[f][1] = A[f][2] = A[f][3] = 0.f; }
        #pragma unroll
        for (int dz = 0; dz < 5; dz++) {
            const int j = ((oz + dz) * 8 + oy) * 8 + h * 4;
            #pragma unroll
            for (int f = 0; f < 5; f++) {
                float4 q = *(const float4*)&F2[f][j];
                A[f][0] += q.x; A[f][1] += q.y; A[f][2] += q.z; A[f][3] += q.w;
            }
        }
        const float inv125 = 1.f / 125.f;
        #pragma unroll
        for (int k = 0; k < 4; k++) {
            float sm = A[0][k] * inv125, tm = A[1][k] * inv125;
            float sv = A[2][k] * inv125 - sm * sm;
            float tv = A[3][k] * inv125 - tm * tm;
            float cross = A[4][k] * inv125 - sm * tm;
            float l = cross * cross / (sv * tv + 1e-5f);
            lsum += (double)l;
        }
    }
    double tot = block_reduce<8>(lsum, red, tid);
    if (tid == 0) ws[LOFF + slot] = tot;
}

// ---------- finalize ----------
__global__ __launch_bounds__(256) void finalize_kernel(const double* __restrict__ ws,
                                                       float* __restrict__ out) {
    __shared__ double red[4];
    double l = 0.0, g = 0.0, j = 0.0, inv = 0.0;
    for (int k = threadIdx.x; k < NB_LNCC; k += 256) l += ws[LOFF + k];
    for (int k = threadIdx.x; k < NB_FUSED; k += 256) {
        g   += ws[GOFF + k];
        j   += ws[JOFF + k];
        inv += ws[IOFF + k];
    }
    double tl = block_reduce<4>(l, red, threadIdx.x);
    double tg = block_reduce<4>(g, red, threadIdx.x);
    double tj = block_reduce<4>(j, red, threadIdx.x);
    double ti = block_reduce<4>(inv, red, threadIdx.x);
    if (threadIdx.x == 0) {
        double li = 1.0 - tl / (double)NN;
        if (isnan(li) || isinf(li)) li = 1.0;
        double grad = tg / (9.0 * 127.0 * 128.0 * 128.0);
        double jac  = tj / ((double)DJ * DJ * DJ);
        double iv = ti / (3.0 * (double)NN);
        if (isnan(iv)) iv = 0.0;
        else if (isinf(iv)) iv = iv > 0.0 ? 1000.0 : 0.0;
        out[0] = (float)(1.0 * li + 0.02 * grad + 0.01 * jac + 0.1 * iv);
    }
}

extern "C" void kernel_launch(void* const* d_in, const int* in_sizes, int n_in,
                              void* d_out, int out_size, void* d_ws, size_t ws_size,
                              hipStream_t stream) {
    const float* src = (const float*)d_in[0];
    const float* tgt = (const float*)d_in[1];
    const float* fwd = (const float*)d_in[2];
    const float* bwd = (const float*)d_in[3];
    double* ws = (double*)d_ws;
    float* out = (float*)d_out;

    mega_kernel<<<6144, 512, 0, stream>>>(src, tgt, fwd, bwd, ws);
    finalize_kernel<<<1, 256, 0, stream>>>(ws, out);
}